// Round 7
// baseline (302.893 us; speedup 1.0000x reference)
//
#include <hip/hip_runtime.h>

#define NN 50000
#define EE 600000
#define HH 128
#define GG 64
#define NPAD 50176   // 196 * 256
#define NR 196       // dst ranges (256 nodes each)
#define RN 256       // nodes per range
#define NSEC3 150528 // 3 * NPAD
#define NBLK3 588    // NSEC3 / 256
#define NSTREAM 4704 // 3*NR*8
#define SCAP 768     // per-stream entry capacity (mean 384, +19 sd)
#define BCAP 3584    // per-bucket staging capacity (mean 3072, +10 sd)

typedef __attribute__((ext_vector_type(8))) short short8;
typedef __attribute__((ext_vector_type(4))) float f32x4;
typedef __attribute__((ext_vector_type(4))) unsigned int u32x4;

__device__ __forceinline__ float bf2f(unsigned int u16) {
    union { unsigned int i; float f; } v; v.i = u16 << 16; return v.f;
}
__device__ __forceinline__ unsigned short f2bf(float f) {
    union { float f; unsigned int i; } v; v.f = f;
    unsigned int u = v.i;
    return (unsigned short)((u + 0x7FFFu + ((u >> 16) & 1u)) >> 16);
}

__device__ __forceinline__ short8 cvt8(f32x4 lo, f32x4 hi) {
    short8 r;
    r[0] = (short)f2bf(lo[0]); r[1] = (short)f2bf(lo[1]);
    r[2] = (short)f2bf(lo[2]); r[3] = (short)f2bf(lo[3]);
    r[4] = (short)f2bf(hi[0]); r[5] = (short)f2bf(hi[1]);
    r[6] = (short)f2bf(hi[2]); r[7] = (short)f2bf(hi[3]);
    return r;
}

// ---------------- phase 1: partition edges into (sec, dst-range, blk&7) streams ----------------
__global__ void k_part(const int* __restrict__ ei, const int* __restrict__ mask,
                       int* __restrict__ scnt, unsigned int* __restrict__ sbuf) {
    int e = blockIdx.x * 256 + threadIdx.x;
    if (e >= EE) return;
    int s = ei[e];
    int d = ei[EE + e];
    int m = mask[e];
    int x8 = blockIdx.x & 7;
    unsigned int pk = (unsigned int)s | ((unsigned int)(d & 255) << 16);
    int rng = d >> 8;
    int b = ((rng) << 3) + x8;                       // sec 0
    int sl = atomicAdd(&scnt[b], 1);
    if (sl < SCAP) sbuf[(size_t)b * SCAP + sl] = pk;
    if (m == 1) {
        b = ((NR + rng) << 3) + x8;                  // sec 1
        sl = atomicAdd(&scnt[b], 1);
        if (sl < SCAP) sbuf[(size_t)b * SCAP + sl] = pk;
    } else if (m == 2) {
        b = ((2 * NR + rng) << 3) + x8;              // sec 2
        sl = atomicAdd(&scnt[b], 1);
        if (sl < SCAP) sbuf[(size_t)b * SCAP + sl] = pk;
    }
}

// ---------------- phase 2: per-bucket LDS histogram -> deg (coalesced) ----------------
__global__ __launch_bounds__(256) void k_cnt(const int* __restrict__ scnt,
                                             const unsigned int* __restrict__ sbuf,
                                             int* __restrict__ deg) {
    __shared__ int lcur[RN];
    int t = threadIdx.x;
    int sec = blockIdx.x / NR, rng = blockIdx.x % NR;
    lcur[t] = 0;
    __syncthreads();
    int sidbase = (sec * NR + rng) * 8;
    for (int x = 0; x < 8; x++) {
        int sid = sidbase + x;
        int cnt = scnt[sid]; if (cnt > SCAP) cnt = SCAP;
        const unsigned int* sb = sbuf + (size_t)sid * SCAP;
        for (int i = t; i < cnt; i += 256)
            atomicAdd(&lcur[sb[i] >> 16], 1);
    }
    __syncthreads();
    deg[sec * NPAD + rng * RN + t] = lcur[t];
}

// in-place: int deg -> float rsqrt(deg+1), all 3 sections
__global__ void k_dinv(int* __restrict__ deg) {
    int i = blockIdx.x * 256 + threadIdx.x;
    if (i >= NN) return;
    int a = deg[i], b = deg[NPAD + i], c = deg[2 * NPAD + i];
    ((float*)deg)[i] = rsqrtf((float)a + 1.0f);
    ((float*)deg)[NPAD + i] = rsqrtf((float)b + 1.0f);
    ((float*)deg)[2 * NPAD + i] = rsqrtf((float)c + 1.0f);
}

// ---------------- hierarchical scan over concatenated deg (3*NPAD) -> rp ----------------
__global__ __launch_bounds__(256) void k_scan1(const int* __restrict__ deg, int* __restrict__ btot) {
    __shared__ int ws[4];
    int t = threadIdx.x, lane = t & 63, w = t >> 6;
    int v = deg[blockIdx.x * 256 + t];
    #pragma unroll
    for (int off = 32; off > 0; off >>= 1) v += __shfl_xor(v, off);
    if (lane == 0) ws[w] = v;
    __syncthreads();
    if (t == 0) btot[blockIdx.x] = ws[0] + ws[1] + ws[2] + ws[3];
}

__global__ __launch_bounds__(1024) void k_scan2(const int* __restrict__ btot, int* __restrict__ boff) {
    __shared__ int ws[16];
    int t = threadIdx.x, lane = t & 63, w = t >> 6;
    int v = (t < NBLK3) ? btot[t] : 0;
    int x = v;
    #pragma unroll
    for (int off = 1; off < 64; off <<= 1) {
        int u = __shfl_up(x, off);
        if (lane >= off) x += u;
    }
    if (lane == 63) ws[w] = x;
    __syncthreads();
    int wo = 0;
    for (int k = 0; k < w; k++) wo += ws[k];
    if (t < NBLK3) boff[t] = wo + x - v;
}

__global__ __launch_bounds__(256) void k_scan3(const int* __restrict__ deg, const int* __restrict__ boff,
                                               int* __restrict__ rp) {
    __shared__ int ws[4];
    int t = threadIdx.x, lane = t & 63, w = t >> 6;
    int i = blockIdx.x * 256 + t;
    int v = deg[i];
    int x = v;
    #pragma unroll
    for (int off = 1; off < 64; off <<= 1) {
        int u = __shfl_up(x, off);
        if (lane >= off) x += u;
    }
    if (lane == 63) ws[w] = x;
    __syncthreads();
    int wo = 0;
    for (int k = 0; k < w; k++) wo += ws[k];
    int r = boff[blockIdx.x] + wo + x - v;
    rp[i] = r;
    if (i == NSEC3 - 1) rp[NSEC3] = r + v;
}

// ---------------- phase 3: per-bucket counting-scatter in LDS -> coalesced csr (ushort) ----------------
__global__ __launch_bounds__(256) void k_build(const int* __restrict__ scnt,
                                               const unsigned int* __restrict__ sbuf,
                                               const int* __restrict__ rp,
                                               unsigned short* __restrict__ csr) {
    __shared__ int lrp[RN + 1];
    __shared__ int lcur[RN];
    __shared__ unsigned short stag[BCAP];
    int t = threadIdx.x;
    int sec = blockIdx.x / NR, rng = blockIdx.x % NR;
    int vd0 = sec * NPAD + rng * RN;
    int base = rp[vd0];
    for (int i = t; i < RN + 1; i += 256) lrp[i] = rp[vd0 + i] - base;
    lcur[t] = 0;
    __syncthreads();
    int sidbase = (sec * NR + rng) * 8;
    for (int x = 0; x < 8; x++) {
        int sid = sidbase + x;
        int cnt = scnt[sid]; if (cnt > SCAP) cnt = SCAP;
        const unsigned int* sb = sbuf + (size_t)sid * SCAP;
        for (int i = t; i < cnt; i += 256) {
            unsigned int p = sb[i];
            int dl = (int)(p >> 16);
            int sl = lrp[dl] + atomicAdd(&lcur[dl], 1);
            if (sl < BCAP) stag[sl] = (unsigned short)(p & 0xffffu);
        }
    }
    __syncthreads();
    int tot = lrp[RN]; if (tot > BCAP) tot = BCAP;
    for (int i = t; i < tot; i += 256) csr[base + i] = stag[i];
}

// ---------------- weights transpose+cvt: wt[n][k] = bf16(w[k][n]) ----------------
__global__ void k_wt(const float* __restrict__ w, unsigned short* __restrict__ wt) {
    int i = blockIdx.x * 256 + threadIdx.x;  // 0..16383
    int k = i >> 7, n = i & 127;
    wt[n * HH + k] = f2bf(w[i]);
}

// ---------------- GEMM (f32 input): h(bf16) = in @ W ----------------
__global__ __launch_bounds__(256) void k_gemm_f(const float* __restrict__ in,
                                                const unsigned short* __restrict__ wt,
                                                unsigned short* __restrict__ h) {
    int w = threadIdx.x >> 6, lane = threadIdx.x & 63;
    int lr = lane & 15, lg = lane >> 4;
    int rowbase = (blockIdx.x * 4 + w) * 16;
    if (rowbase >= NN) return;
    int arow = rowbase + lr;
    const f32x4* ap = (const f32x4*)(in + (size_t)arow * HH + lg * 8);
    short8 a0 = cvt8(ap[0], ap[1]);
    short8 a1 = cvt8(ap[8], ap[9]);
    short8 a2 = cvt8(ap[16], ap[17]);
    short8 a3 = cvt8(ap[24], ap[25]);
    f32x4 acc[8];
    #pragma unroll
    for (int i = 0; i < 8; i++) acc[i] = (f32x4){0.f, 0.f, 0.f, 0.f};
    const unsigned short* wbase = wt + lr * HH + lg * 8;
    #pragma unroll
    for (int nc = 0; nc < 8; nc++) {
        const short8* bp = (const short8*)(wbase + nc * 16 * HH);
        short8 b0 = bp[0], b1 = bp[4], b2 = bp[8], b3 = bp[12];
        acc[nc] = __builtin_amdgcn_mfma_f32_16x16x32_bf16(a0, b0, acc[nc], 0, 0, 0);
        acc[nc] = __builtin_amdgcn_mfma_f32_16x16x32_bf16(a1, b1, acc[nc], 0, 0, 0);
        acc[nc] = __builtin_amdgcn_mfma_f32_16x16x32_bf16(a2, b2, acc[nc], 0, 0, 0);
        acc[nc] = __builtin_amdgcn_mfma_f32_16x16x32_bf16(a3, b3, acc[nc], 0, 0, 0);
    }
    int orow = rowbase + lg * 4;
    #pragma unroll
    for (int nc = 0; nc < 8; nc++) {
        #pragma unroll
        for (int j = 0; j < 4; j++) {
            h[(size_t)(orow + j) * HH + nc * 16 + lr] = f2bf(acc[nc][j]);
        }
    }
}

// ---------------- GEMM (bf16 input): h(bf16) = in @ W ----------------
__global__ __launch_bounds__(256) void k_gemm_b(const unsigned short* __restrict__ in,
                                                const unsigned short* __restrict__ wt,
                                                unsigned short* __restrict__ h) {
    int w = threadIdx.x >> 6, lane = threadIdx.x & 63;
    int lr = lane & 15, lg = lane >> 4;
    int rowbase = (blockIdx.x * 4 + w) * 16;
    if (rowbase >= NN) return;
    int arow = rowbase + lr;
    const short8* ap = (const short8*)(in + (size_t)arow * HH + lg * 8);
    short8 a0 = ap[0], a1 = ap[4], a2 = ap[8], a3 = ap[12];
    f32x4 acc[8];
    #pragma unroll
    for (int i = 0; i < 8; i++) acc[i] = (f32x4){0.f, 0.f, 0.f, 0.f};
    const unsigned short* wbase = wt + lr * HH + lg * 8;
    #pragma unroll
    for (int nc = 0; nc < 8; nc++) {
        const short8* bp = (const short8*)(wbase + nc * 16 * HH);
        short8 b0 = bp[0], b1 = bp[4], b2 = bp[8], b3 = bp[12];
        acc[nc] = __builtin_amdgcn_mfma_f32_16x16x32_bf16(a0, b0, acc[nc], 0, 0, 0);
        acc[nc] = __builtin_amdgcn_mfma_f32_16x16x32_bf16(a1, b1, acc[nc], 0, 0, 0);
        acc[nc] = __builtin_amdgcn_mfma_f32_16x16x32_bf16(a2, b2, acc[nc], 0, 0, 0);
        acc[nc] = __builtin_amdgcn_mfma_f32_16x16x32_bf16(a3, b3, acc[nc], 0, 0, 0);
    }
    int orow = rowbase + lg * 4;
    #pragma unroll
    for (int nc = 0; nc < 8; nc++) {
        #pragma unroll
        for (int j = 0; j < 4; j++) {
            h[(size_t)(orow + j) * HH + nc * 16 + lr] = f2bf(acc[nc][j]);
        }
    }
}

// ---------------- aggregation: 16 lanes/node, pre-filtered CSR section (ushort) ----------------
__global__ __launch_bounds__(256) void k_agg(const unsigned short* __restrict__ h,
                                             const float* __restrict__ dinv,
                                             const unsigned short* __restrict__ csr,
                                             const int* __restrict__ rp,
                                             const float* __restrict__ bias,
                                             unsigned short* __restrict__ g,
                                             int relu) {
    int tid = threadIdx.x;
    int n = blockIdx.x * 16 + (tid >> 4);   // NN % 16 == 0 -> always < NN
    int l = tid & 15;
    float di = dinv[n];
    float c = di * di;
    u32x4 hv = *(const u32x4*)(h + (size_t)n * HH + l * 8);
    float acc0 = bf2f(hv[0] & 0xffffu) * c, acc1 = bf2f(hv[0] >> 16) * c;
    float acc2 = bf2f(hv[1] & 0xffffu) * c, acc3 = bf2f(hv[1] >> 16) * c;
    float acc4 = bf2f(hv[2] & 0xffffu) * c, acc5 = bf2f(hv[2] >> 16) * c;
    float acc6 = bf2f(hv[3] & 0xffffu) * c, acc7 = bf2f(hv[3] >> 16) * c;
    int e = rp[n], end = rp[n + 1];
    for (; e + 1 < end; e += 2) {
        int s0 = (int)csr[e];
        int s1 = (int)csr[e + 1];
        float w0 = dinv[s0] * di;
        float w1 = dinv[s1] * di;
        u32x4 v0 = *(const u32x4*)(h + (size_t)s0 * HH + l * 8);
        u32x4 v1 = *(const u32x4*)(h + (size_t)s1 * HH + l * 8);
        acc0 += w0 * bf2f(v0[0] & 0xffffu); acc1 += w0 * bf2f(v0[0] >> 16);
        acc2 += w0 * bf2f(v0[1] & 0xffffu); acc3 += w0 * bf2f(v0[1] >> 16);
        acc4 += w0 * bf2f(v0[2] & 0xffffu); acc5 += w0 * bf2f(v0[2] >> 16);
        acc6 += w0 * bf2f(v0[3] & 0xffffu); acc7 += w0 * bf2f(v0[3] >> 16);
        acc0 += w1 * bf2f(v1[0] & 0xffffu); acc1 += w1 * bf2f(v1[0] >> 16);
        acc2 += w1 * bf2f(v1[1] & 0xffffu); acc3 += w1 * bf2f(v1[1] >> 16);
        acc4 += w1 * bf2f(v1[2] & 0xffffu); acc5 += w1 * bf2f(v1[2] >> 16);
        acc6 += w1 * bf2f(v1[3] & 0xffffu); acc7 += w1 * bf2f(v1[3] >> 16);
    }
    if (e < end) {
        int s0 = (int)csr[e];
        float w0 = dinv[s0] * di;
        u32x4 v0 = *(const u32x4*)(h + (size_t)s0 * HH + l * 8);
        acc0 += w0 * bf2f(v0[0] & 0xffffu); acc1 += w0 * bf2f(v0[0] >> 16);
        acc2 += w0 * bf2f(v0[1] & 0xffffu); acc3 += w0 * bf2f(v0[1] >> 16);
        acc4 += w0 * bf2f(v0[2] & 0xffffu); acc5 += w0 * bf2f(v0[2] >> 16);
        acc6 += w0 * bf2f(v0[3] & 0xffffu); acc7 += w0 * bf2f(v0[3] >> 16);
    }
    f32x4 bp0 = *(const f32x4*)(bias + l * 8);
    f32x4 bp1 = *(const f32x4*)(bias + l * 8 + 4);
    acc0 += bp0[0]; acc1 += bp0[1]; acc2 += bp0[2]; acc3 += bp0[3];
    acc4 += bp1[0]; acc5 += bp1[1]; acc6 += bp1[2]; acc7 += bp1[3];
    if (relu) {
        acc0 = fmaxf(acc0, 0.f); acc1 = fmaxf(acc1, 0.f);
        acc2 = fmaxf(acc2, 0.f); acc3 = fmaxf(acc3, 0.f);
        acc4 = fmaxf(acc4, 0.f); acc5 = fmaxf(acc5, 0.f);
        acc6 = fmaxf(acc6, 0.f); acc7 = fmaxf(acc7, 0.f);
    }
    u32x4 o;
    o[0] = (unsigned int)f2bf(acc0) | ((unsigned int)f2bf(acc1) << 16);
    o[1] = (unsigned int)f2bf(acc2) | ((unsigned int)f2bf(acc3) << 16);
    o[2] = (unsigned int)f2bf(acc4) | ((unsigned int)f2bf(acc5) << 16);
    o[3] = (unsigned int)f2bf(acc6) | ((unsigned int)f2bf(acc7) << 16);
    *(u32x4*)(g + (size_t)n * HH + l * 8) = o;
}

// ---------------- pool stage 1 ----------------
__global__ __launch_bounds__(128) void k_pool_part(const unsigned short* __restrict__ g3,
                                                   const int* __restrict__ batch,
                                                   float* __restrict__ sums) {
    int t = threadIdx.x;
    int n0 = blockIdx.x * 64;
    int n1 = n0 + 64; if (n1 > NN) n1 = NN;
    int curb = batch[n0];
    float acc = 0.f;
    for (int n = n0; n < n1; n++) {
        int b = batch[n];
        if (b != curb) {
            atomicAdd(&sums[curb * HH + t], acc);
            acc = 0.f;
            curb = b;
        }
        acc += bf2f((unsigned int)g3[(size_t)n * HH + t]);
    }
    atomicAdd(&sums[curb * HH + t], acc);
}

// ---------------- pool stage 2 + head ----------------
__device__ __forceinline__ int lbound(const int* a, int n, int key) {
    int lo = 0, hi = n;
    while (lo < hi) { int mid = (lo + hi) >> 1; if (a[mid] < key) lo = mid + 1; else hi = mid; }
    return lo;
}

__global__ __launch_bounds__(128) void k_head(const float* __restrict__ sums,
                                              const int* __restrict__ batch,
                                              const float* __restrict__ Wl,
                                              const float* __restrict__ bl,
                                              float* __restrict__ out) {
    int gid = blockIdx.x;
    int t = threadIdx.x;
    int lo = lbound(batch, NN, gid);
    int hi = lbound(batch, NN, gid + 1);
    float cnt = (float)(hi - lo);
    if (cnt < 1.f) cnt = 1.f;
    float prod = (sums[gid * HH + t] / cnt) * Wl[t];
    __shared__ float sm[128];
    sm[t] = prod;
    __syncthreads();
    for (int off = 64; off > 0; off >>= 1) {
        if (t < off) sm[t] += sm[t + off];
        __syncthreads();
    }
    if (t == 0) out[gid] = sm[0] + bl[0];
}

// ---------------- launcher ----------------
extern "C" void kernel_launch(void* const* d_in, const int* in_sizes, int n_in,
                              void* d_out, int out_size, void* d_ws, size_t ws_size,
                              hipStream_t stream) {
    const float* x    = (const float*)d_in[0];
    const int*   ei   = (const int*)d_in[1];
    const int*   mask = (const int*)d_in[2];
    const int*   batch= (const int*)d_in[3];
    const float* W1   = (const float*)d_in[4];
    const float* b1   = (const float*)d_in[5];
    const float* W2   = (const float*)d_in[6];
    const float* b2   = (const float*)d_in[7];
    const float* W3   = (const float*)d_in[8];
    const float* b3   = (const float*)d_in[9];
    const float* Wl   = (const float*)d_in[10];
    const float* bl   = (const float*)d_in[11];
    float* out = (float*)d_out;

    char* ws = (char*)d_ws;
    unsigned short* g = (unsigned short*)(ws + 0);          // 12,800,000
    unsigned short* h = (unsigned short*)(ws + 12800000);   // 12,800,000
    unsigned short* wt1 = (unsigned short*)(ws + 25600000); // 98,304 (3x)
    unsigned short* wt2 = wt1 + 16384;
    unsigned short* wt3 = wt2 + 16384;
    int* deg  = (int*)(ws + 25698304);                      // 3*NPAD int -> dinv f32 in place
    int* rp   = (int*)(ws + 26300416);                      // (NSEC3+1) int, reserve 602,624
    int* btot = (int*)(ws + 26903040);                      // 4096
    int* boff = (int*)(ws + 26907136);                      // 4096
    int* scnt = (int*)(ws + 26911232);                      // NSTREAM int, reserve 20,480
    unsigned short* csr = (unsigned short*)(ws + 26931712); // 1.2M ushort = 2,400,000
    unsigned int* sbuf = (unsigned int*)(ws + 29331712);    // NSTREAM*SCAP*4 = 14,450,688
    float* sums = (float*)(ws + 43782400);                  // 64*128 f32 = 32,768
    // total = 43,815,168 bytes

    float* dinv1 = (float*)deg;
    float* dinv2 = dinv1 + NPAD;
    float* dinv3 = dinv2 + NPAD;

    hipMemsetAsync(scnt, 0, (size_t)NSTREAM * sizeof(int), stream);
    hipMemsetAsync(sums, 0, (size_t)GG * HH * sizeof(float), stream);

    dim3 b256(256);
    k_part<<<dim3((EE + 255) / 256), b256, 0, stream>>>(ei, mask, scnt, sbuf);
    k_cnt<<<dim3(3 * NR), b256, 0, stream>>>(scnt, sbuf, deg);
    k_scan1<<<dim3(NBLK3), b256, 0, stream>>>(deg, btot);
    k_scan2<<<dim3(1), dim3(1024), 0, stream>>>(btot, boff);
    k_scan3<<<dim3(NBLK3), b256, 0, stream>>>(deg, boff, rp);
    k_dinv<<<dim3((NN + 255) / 256), b256, 0, stream>>>(deg);
    k_build<<<dim3(3 * NR), b256, 0, stream>>>(scnt, sbuf, rp, csr);

    k_wt<<<dim3(64), b256, 0, stream>>>(W1, wt1);
    k_wt<<<dim3(64), b256, 0, stream>>>(W2, wt2);
    k_wt<<<dim3(64), b256, 0, stream>>>(W3, wt3);

    dim3 ggrid((NN + 63) / 64);   // 782 blocks (gemm)
    dim3 agrid(NN / 16);          // 3125 blocks (agg)

    // layer 1: all edges (section 0)
    k_gemm_f<<<ggrid, b256, 0, stream>>>(x, wt1, h);
    k_agg<<<agrid, b256, 0, stream>>>(h, dinv1, csr, rp, b1, g, 1);
    // layer 2: mask==1 (section 1)
    k_gemm_b<<<ggrid, b256, 0, stream>>>(g, wt2, h);
    k_agg<<<agrid, b256, 0, stream>>>(h, dinv2, csr, rp + NPAD, b2, g, 1);
    // layer 3: mask==2 (section 2), no relu
    k_gemm_b<<<ggrid, b256, 0, stream>>>(g, wt3, h);
    k_agg<<<agrid, b256, 0, stream>>>(h, dinv3, csr, rp + 2 * NPAD, b3, g, 0);

    k_pool_part<<<dim3((NN + 63) / 64), dim3(128), 0, stream>>>(g, batch, sums);
    k_head<<<dim3(GG), dim3(128), 0, stream>>>(sums, batch, Wl, bl, out);
}

// Round 8
// 197.203 us; speedup vs baseline: 1.5359x; 1.5359x over previous
//
#include <hip/hip_runtime.h>

#define NN 50000
#define EE 600000
#define HH 128
#define GG 64
#define NPAD 50176   // 196 * 256
#define NR 196       // dst ranges (256 nodes each)
#define RN 256
#define NSEC3 150528 // 3 * NPAD
#define NBLK3 588    // NSEC3 / 256
#define EPB 3072     // edges per k_part block (12 per thread)
#define SCAP 3584    // per-stream capacity (mean 3061, sd ~55, +9.5 sd)
#define STAGB 7168   // k_build staging (provably >= c0+c1+c2 since c1+c2<=c0<=SCAP)

typedef __attribute__((ext_vector_type(8))) short short8;
typedef __attribute__((ext_vector_type(4))) float f32x4;
typedef __attribute__((ext_vector_type(4))) unsigned int u32x4;

__device__ __forceinline__ float bf2f(unsigned int u16) {
    union { unsigned int i; float f; } v; v.i = u16 << 16; return v.f;
}
__device__ __forceinline__ unsigned short f2bf(float f) {
    union { float f; unsigned int i; } v; v.f = f;
    unsigned int u = v.i;
    return (unsigned short)((u + 0x7FFFu + ((u >> 16) & 1u)) >> 16);
}

__device__ __forceinline__ short8 cvt8(f32x4 lo, f32x4 hi) {
    short8 r;
    r[0] = (short)f2bf(lo[0]); r[1] = (short)f2bf(lo[1]);
    r[2] = (short)f2bf(lo[2]); r[3] = (short)f2bf(lo[3]);
    r[4] = (short)f2bf(hi[0]); r[5] = (short)f2bf(hi[1]);
    r[6] = (short)f2bf(hi[2]); r[7] = (short)f2bf(hi[3]);
    return r;
}

// ---------------- phase 1: partition edges into 196 dst-range streams ----------------
// entry = src(16) | d_local(8)<<16 | mask(2)<<24. Per (block,bin): one global
// atomic reserve; region written by this block only -> L2 merges lines.
__global__ __launch_bounds__(256) void k_part(const int* __restrict__ ei, const int* __restrict__ mask,
                                              int* __restrict__ scnt, unsigned int* __restrict__ sbuf) {
    __shared__ int bcnt[256];
    __shared__ int bcur[256];
    __shared__ int gbase[256];
    int t = threadIdx.x;
    int e0 = blockIdx.x * EPB;
    unsigned int pk[12]; int bin[12];
    bcnt[t] = 0; bcur[t] = 0;
    __syncthreads();
    #pragma unroll
    for (int j = 0; j < 12; j++) {
        int e = e0 + j * 256 + t;
        if (e < EE) {
            int s = ei[e];
            int d = ei[EE + e];
            int m = mask[e];
            pk[j] = (unsigned int)s | ((unsigned int)(d & 255) << 16) | ((unsigned int)m << 24);
            bin[j] = d >> 8;
            atomicAdd(&bcnt[bin[j]], 1);
        } else bin[j] = -1;
    }
    __syncthreads();
    int v = bcnt[t];
    gbase[t] = (v > 0) ? atomicAdd(&scnt[t], v) : 0;
    __syncthreads();
    #pragma unroll
    for (int j = 0; j < 12; j++) {
        if (bin[j] >= 0) {
            int b = bin[j];
            int pos = gbase[b] + atomicAdd(&bcur[b], 1);
            if (pos < SCAP) sbuf[(size_t)b * SCAP + pos] = pk[j];
        }
    }
}

// ---------------- phase 2: per-stream histograms -> deg (3 sections) + dinv ----------------
__global__ __launch_bounds__(256) void k_cnt(const int* __restrict__ scnt,
                                             const unsigned int* __restrict__ sbuf,
                                             int* __restrict__ deg, float* __restrict__ dinv) {
    __shared__ int l0[RN], l1[RN], l2[RN];
    int t = threadIdx.x;
    int rng = blockIdx.x;
    l0[t] = 0; l1[t] = 0; l2[t] = 0;
    __syncthreads();
    int cnt = scnt[rng]; if (cnt > SCAP) cnt = SCAP;
    const unsigned int* sb = sbuf + (size_t)rng * SCAP;
    for (int i = t; i < cnt; i += 256) {
        unsigned int p = sb[i];
        int dl = (int)((p >> 16) & 255u);
        int m = (int)(p >> 24);
        atomicAdd(&l0[dl], 1);
        if (m == 1) atomicAdd(&l1[dl], 1);
        else if (m == 2) atomicAdd(&l2[dl], 1);
    }
    __syncthreads();
    int node = rng * RN + t;
    int a = l0[t], b = l1[t], c = l2[t];
    deg[node] = a;
    deg[NPAD + node] = b;
    deg[2 * NPAD + node] = c;
    dinv[node] = rsqrtf((float)a + 1.0f);
    dinv[NPAD + node] = rsqrtf((float)b + 1.0f);
    dinv[2 * NPAD + node] = rsqrtf((float)c + 1.0f);
}

// ---------------- hierarchical scan over concatenated deg (3*NPAD) -> rp ----------------
__global__ __launch_bounds__(256) void k_scan1(const int* __restrict__ deg, int* __restrict__ btot) {
    __shared__ int ws[4];
    int t = threadIdx.x, lane = t & 63, w = t >> 6;
    int v = deg[blockIdx.x * 256 + t];
    #pragma unroll
    for (int off = 32; off > 0; off >>= 1) v += __shfl_xor(v, off);
    if (lane == 0) ws[w] = v;
    __syncthreads();
    if (t == 0) btot[blockIdx.x] = ws[0] + ws[1] + ws[2] + ws[3];
}

__global__ __launch_bounds__(1024) void k_scan2(const int* __restrict__ btot, int* __restrict__ boff) {
    __shared__ int ws[16];
    int t = threadIdx.x, lane = t & 63, w = t >> 6;
    int v = (t < NBLK3) ? btot[t] : 0;
    int x = v;
    #pragma unroll
    for (int off = 1; off < 64; off <<= 1) {
        int u = __shfl_up(x, off);
        if (lane >= off) x += u;
    }
    if (lane == 63) ws[w] = x;
    __syncthreads();
    int wo = 0;
    for (int k = 0; k < w; k++) wo += ws[k];
    if (t < NBLK3) boff[t] = wo + x - v;
}

__global__ __launch_bounds__(256) void k_scan3(const int* __restrict__ deg, const int* __restrict__ boff,
                                               int* __restrict__ rp) {
    __shared__ int ws[4];
    int t = threadIdx.x, lane = t & 63, w = t >> 6;
    int i = blockIdx.x * 256 + t;
    int v = deg[i];
    int x = v;
    #pragma unroll
    for (int off = 1; off < 64; off <<= 1) {
        int u = __shfl_up(x, off);
        if (lane >= off) x += u;
    }
    if (lane == 63) ws[w] = x;
    __syncthreads();
    int wo = 0;
    for (int k = 0; k < w; k++) wo += ws[k];
    int r = boff[blockIdx.x] + wo + x - v;
    rp[i] = r;
    if (i == NSEC3 - 1) rp[NSEC3] = r + v;
}

// ---------------- phase 3: one block per range; build all 3 csr sections coalesced ----------------
__global__ __launch_bounds__(256) void k_build(const int* __restrict__ scnt,
                                               const unsigned int* __restrict__ sbuf,
                                               const int* __restrict__ rp,
                                               unsigned short* __restrict__ csr) {
    __shared__ int lrp0[RN + 1], lrp1[RN + 1], lrp2[RN + 1];
    __shared__ int lc0[RN], lc1[RN], lc2[RN];
    __shared__ unsigned short stag[STAGB];
    int t = threadIdx.x;
    int rng = blockIdx.x;
    int vd0 = rng * RN;
    int base0 = rp[vd0], base1 = rp[NPAD + vd0], base2 = rp[2 * NPAD + vd0];
    for (int i = t; i < RN + 1; i += 256) {
        lrp0[i] = rp[vd0 + i] - base0;
        lrp1[i] = rp[NPAD + vd0 + i] - base1;
        lrp2[i] = rp[2 * NPAD + vd0 + i] - base2;
    }
    lc0[t] = 0; lc1[t] = 0; lc2[t] = 0;
    __syncthreads();
    int c0 = lrp0[RN], c1 = lrp1[RN], c2 = lrp2[RN];
    int cnt = scnt[rng]; if (cnt > SCAP) cnt = SCAP;
    const unsigned int* sb = sbuf + (size_t)rng * SCAP;
    for (int i = t; i < cnt; i += 256) {
        unsigned int p = sb[i];
        unsigned short src = (unsigned short)(p & 0xffffu);
        int dl = (int)((p >> 16) & 255u);
        int m = (int)(p >> 24);
        int sl = lrp0[dl] + atomicAdd(&lc0[dl], 1);
        stag[sl] = src;
        if (m == 1) { sl = c0 + lrp1[dl] + atomicAdd(&lc1[dl], 1); stag[sl] = src; }
        else if (m == 2) { sl = c0 + c1 + lrp2[dl] + atomicAdd(&lc2[dl], 1); stag[sl] = src; }
    }
    __syncthreads();
    for (int i = t; i < c0; i += 256) csr[base0 + i] = stag[i];
    for (int i = t; i < c1; i += 256) csr[base1 + i] = stag[c0 + i];
    for (int i = t; i < c2; i += 256) csr[base2 + i] = stag[c0 + c1 + i];
}

// ---------------- weights transpose+cvt, all 3 in one launch ----------------
__global__ void k_wt3(const float* __restrict__ W1, const float* __restrict__ W2,
                      const float* __restrict__ W3, unsigned short* __restrict__ wt) {
    int i = blockIdx.x * 256 + threadIdx.x;  // 0..49151
    int which = i >> 14;
    int r = i & 16383;
    const float* w = (which == 0) ? W1 : (which == 1) ? W2 : W3;
    int k = r >> 7, n = r & 127;
    wt[which * 16384 + n * HH + k] = f2bf(w[r]);
}

// ---------------- GEMM (f32 input): h(bf16) = in @ W ----------------
__global__ __launch_bounds__(256) void k_gemm_f(const float* __restrict__ in,
                                                const unsigned short* __restrict__ wt,
                                                unsigned short* __restrict__ h) {
    int w = threadIdx.x >> 6, lane = threadIdx.x & 63;
    int lr = lane & 15, lg = lane >> 4;
    int rowbase = (blockIdx.x * 4 + w) * 16;
    if (rowbase >= NN) return;
    int arow = rowbase + lr;
    const f32x4* ap = (const f32x4*)(in + (size_t)arow * HH + lg * 8);
    short8 a0 = cvt8(ap[0], ap[1]);
    short8 a1 = cvt8(ap[8], ap[9]);
    short8 a2 = cvt8(ap[16], ap[17]);
    short8 a3 = cvt8(ap[24], ap[25]);
    f32x4 acc[8];
    #pragma unroll
    for (int i = 0; i < 8; i++) acc[i] = (f32x4){0.f, 0.f, 0.f, 0.f};
    const unsigned short* wbase = wt + lr * HH + lg * 8;
    #pragma unroll
    for (int nc = 0; nc < 8; nc++) {
        const short8* bp = (const short8*)(wbase + nc * 16 * HH);
        short8 b0 = bp[0], b1 = bp[4], b2 = bp[8], b3 = bp[12];
        acc[nc] = __builtin_amdgcn_mfma_f32_16x16x32_bf16(a0, b0, acc[nc], 0, 0, 0);
        acc[nc] = __builtin_amdgcn_mfma_f32_16x16x32_bf16(a1, b1, acc[nc], 0, 0, 0);
        acc[nc] = __builtin_amdgcn_mfma_f32_16x16x32_bf16(a2, b2, acc[nc], 0, 0, 0);
        acc[nc] = __builtin_amdgcn_mfma_f32_16x16x32_bf16(a3, b3, acc[nc], 0, 0, 0);
    }
    int orow = rowbase + lg * 4;
    #pragma unroll
    for (int nc = 0; nc < 8; nc++) {
        #pragma unroll
        for (int j = 0; j < 4; j++) {
            h[(size_t)(orow + j) * HH + nc * 16 + lr] = f2bf(acc[nc][j]);
        }
    }
}

// ---------------- GEMM (bf16 input): h(bf16) = in @ W ----------------
__global__ __launch_bounds__(256) void k_gemm_b(const unsigned short* __restrict__ in,
                                                const unsigned short* __restrict__ wt,
                                                unsigned short* __restrict__ h) {
    int w = threadIdx.x >> 6, lane = threadIdx.x & 63;
    int lr = lane & 15, lg = lane >> 4;
    int rowbase = (blockIdx.x * 4 + w) * 16;
    if (rowbase >= NN) return;
    int arow = rowbase + lr;
    const short8* ap = (const short8*)(in + (size_t)arow * HH + lg * 8);
    short8 a0 = ap[0], a1 = ap[4], a2 = ap[8], a3 = ap[12];
    f32x4 acc[8];
    #pragma unroll
    for (int i = 0; i < 8; i++) acc[i] = (f32x4){0.f, 0.f, 0.f, 0.f};
    const unsigned short* wbase = wt + lr * HH + lg * 8;
    #pragma unroll
    for (int nc = 0; nc < 8; nc++) {
        const short8* bp = (const short8*)(wbase + nc * 16 * HH);
        short8 b0 = bp[0], b1 = bp[4], b2 = bp[8], b3 = bp[12];
        acc[nc] = __builtin_amdgcn_mfma_f32_16x16x32_bf16(a0, b0, acc[nc], 0, 0, 0);
        acc[nc] = __builtin_amdgcn_mfma_f32_16x16x32_bf16(a1, b1, acc[nc], 0, 0, 0);
        acc[nc] = __builtin_amdgcn_mfma_f32_16x16x32_bf16(a2, b2, acc[nc], 0, 0, 0);
        acc[nc] = __builtin_amdgcn_mfma_f32_16x16x32_bf16(a3, b3, acc[nc], 0, 0, 0);
    }
    int orow = rowbase + lg * 4;
    #pragma unroll
    for (int nc = 0; nc < 8; nc++) {
        #pragma unroll
        for (int j = 0; j < 4; j++) {
            h[(size_t)(orow + j) * HH + nc * 16 + lr] = f2bf(acc[nc][j]);
        }
    }
}

// ---------------- aggregation: 16 lanes/node, pre-filtered CSR section (ushort) ----------------
__global__ __launch_bounds__(256) void k_agg(const unsigned short* __restrict__ h,
                                             const float* __restrict__ dinv,
                                             const unsigned short* __restrict__ csr,
                                             const int* __restrict__ rp,
                                             const float* __restrict__ bias,
                                             unsigned short* __restrict__ g,
                                             int relu) {
    int tid = threadIdx.x;
    int n = blockIdx.x * 16 + (tid >> 4);
    int l = tid & 15;
    float di = dinv[n];
    float c = di * di;
    u32x4 hv = *(const u32x4*)(h + (size_t)n * HH + l * 8);
    float acc0 = bf2f(hv[0] & 0xffffu) * c, acc1 = bf2f(hv[0] >> 16) * c;
    float acc2 = bf2f(hv[1] & 0xffffu) * c, acc3 = bf2f(hv[1] >> 16) * c;
    float acc4 = bf2f(hv[2] & 0xffffu) * c, acc5 = bf2f(hv[2] >> 16) * c;
    float acc6 = bf2f(hv[3] & 0xffffu) * c, acc7 = bf2f(hv[3] >> 16) * c;
    int e = rp[n], end = rp[n + 1];
    for (; e + 1 < end; e += 2) {
        int s0 = (int)csr[e];
        int s1 = (int)csr[e + 1];
        float w0 = dinv[s0] * di;
        float w1 = dinv[s1] * di;
        u32x4 v0 = *(const u32x4*)(h + (size_t)s0 * HH + l * 8);
        u32x4 v1 = *(const u32x4*)(h + (size_t)s1 * HH + l * 8);
        acc0 += w0 * bf2f(v0[0] & 0xffffu); acc1 += w0 * bf2f(v0[0] >> 16);
        acc2 += w0 * bf2f(v0[1] & 0xffffu); acc3 += w0 * bf2f(v0[1] >> 16);
        acc4 += w0 * bf2f(v0[2] & 0xffffu); acc5 += w0 * bf2f(v0[2] >> 16);
        acc6 += w0 * bf2f(v0[3] & 0xffffu); acc7 += w0 * bf2f(v0[3] >> 16);
        acc0 += w1 * bf2f(v1[0] & 0xffffu); acc1 += w1 * bf2f(v1[0] >> 16);
        acc2 += w1 * bf2f(v1[1] & 0xffffu); acc3 += w1 * bf2f(v1[1] >> 16);
        acc4 += w1 * bf2f(v1[2] & 0xffffu); acc5 += w1 * bf2f(v1[2] >> 16);
        acc6 += w1 * bf2f(v1[3] & 0xffffu); acc7 += w1 * bf2f(v1[3] >> 16);
    }
    if (e < end) {
        int s0 = (int)csr[e];
        float w0 = dinv[s0] * di;
        u32x4 v0 = *(const u32x4*)(h + (size_t)s0 * HH + l * 8);
        acc0 += w0 * bf2f(v0[0] & 0xffffu); acc1 += w0 * bf2f(v0[0] >> 16);
        acc2 += w0 * bf2f(v0[1] & 0xffffu); acc3 += w0 * bf2f(v0[1] >> 16);
        acc4 += w0 * bf2f(v0[2] & 0xffffu); acc5 += w0 * bf2f(v0[2] >> 16);
        acc6 += w0 * bf2f(v0[3] & 0xffffu); acc7 += w0 * bf2f(v0[3] >> 16);
    }
    f32x4 bp0 = *(const f32x4*)(bias + l * 8);
    f32x4 bp1 = *(const f32x4*)(bias + l * 8 + 4);
    acc0 += bp0[0]; acc1 += bp0[1]; acc2 += bp0[2]; acc3 += bp0[3];
    acc4 += bp1[0]; acc5 += bp1[1]; acc6 += bp1[2]; acc7 += bp1[3];
    if (relu) {
        acc0 = fmaxf(acc0, 0.f); acc1 = fmaxf(acc1, 0.f);
        acc2 = fmaxf(acc2, 0.f); acc3 = fmaxf(acc3, 0.f);
        acc4 = fmaxf(acc4, 0.f); acc5 = fmaxf(acc5, 0.f);
        acc6 = fmaxf(acc6, 0.f); acc7 = fmaxf(acc7, 0.f);
    }
    u32x4 o;
    o[0] = (unsigned int)f2bf(acc0) | ((unsigned int)f2bf(acc1) << 16);
    o[1] = (unsigned int)f2bf(acc2) | ((unsigned int)f2bf(acc3) << 16);
    o[2] = (unsigned int)f2bf(acc4) | ((unsigned int)f2bf(acc5) << 16);
    o[3] = (unsigned int)f2bf(acc6) | ((unsigned int)f2bf(acc7) << 16);
    *(u32x4*)(g + (size_t)n * HH + l * 8) = o;
}

// ---------------- pool stage 1 ----------------
__global__ __launch_bounds__(128) void k_pool_part(const unsigned short* __restrict__ g3,
                                                   const int* __restrict__ batch,
                                                   float* __restrict__ sums) {
    int t = threadIdx.x;
    int n0 = blockIdx.x * 64;
    int n1 = n0 + 64; if (n1 > NN) n1 = NN;
    int curb = batch[n0];
    float acc = 0.f;
    for (int n = n0; n < n1; n++) {
        int b = batch[n];
        if (b != curb) {
            atomicAdd(&sums[curb * HH + t], acc);
            acc = 0.f;
            curb = b;
        }
        acc += bf2f((unsigned int)g3[(size_t)n * HH + t]);
    }
    atomicAdd(&sums[curb * HH + t], acc);
}

// ---------------- pool stage 2 + head ----------------
__device__ __forceinline__ int lbound(const int* a, int n, int key) {
    int lo = 0, hi = n;
    while (lo < hi) { int mid = (lo + hi) >> 1; if (a[mid] < key) lo = mid + 1; else hi = mid; }
    return lo;
}

__global__ __launch_bounds__(128) void k_head(const float* __restrict__ sums,
                                              const int* __restrict__ batch,
                                              const float* __restrict__ Wl,
                                              const float* __restrict__ bl,
                                              float* __restrict__ out) {
    int gid = blockIdx.x;
    int t = threadIdx.x;
    int lo = lbound(batch, NN, gid);
    int hi = lbound(batch, NN, gid + 1);
    float cnt = (float)(hi - lo);
    if (cnt < 1.f) cnt = 1.f;
    float prod = (sums[gid * HH + t] / cnt) * Wl[t];
    __shared__ float sm[128];
    sm[t] = prod;
    __syncthreads();
    for (int off = 64; off > 0; off >>= 1) {
        if (t < off) sm[t] += sm[t + off];
        __syncthreads();
    }
    if (t == 0) out[gid] = sm[0] + bl[0];
}

// ---------------- launcher ----------------
extern "C" void kernel_launch(void* const* d_in, const int* in_sizes, int n_in,
                              void* d_out, int out_size, void* d_ws, size_t ws_size,
                              hipStream_t stream) {
    const float* x    = (const float*)d_in[0];
    const int*   ei   = (const int*)d_in[1];
    const int*   mask = (const int*)d_in[2];
    const int*   batch= (const int*)d_in[3];
    const float* W1   = (const float*)d_in[4];
    const float* b1   = (const float*)d_in[5];
    const float* W2   = (const float*)d_in[6];
    const float* b2   = (const float*)d_in[7];
    const float* W3   = (const float*)d_in[8];
    const float* b3   = (const float*)d_in[9];
    const float* Wl   = (const float*)d_in[10];
    const float* bl   = (const float*)d_in[11];
    float* out = (float*)d_out;

    char* ws = (char*)d_ws;
    unsigned short* g = (unsigned short*)(ws + 0);          // 12,800,000
    unsigned short* h = (unsigned short*)(ws + 12800000);   // 12,800,000
    unsigned short* wt1 = (unsigned short*)(ws + 25600000); // 98,304 (3x16384 ushort)
    unsigned short* wt2 = wt1 + 16384;
    unsigned short* wt3 = wt2 + 16384;
    int* deg   = (int*)(ws + 25698304);                     // 3*NPAD int = 602,112
    float* dinv= (float*)(ws + 26300416);                   // 3*NPAD f32 = 602,112
    int* rp    = (int*)(ws + 26902528);                     // (NSEC3+1) int, reserve 602,624
    int* btot  = (int*)(ws + 27505152);                     // 4096
    int* boff  = (int*)(ws + 27509248);                     // 4096
    int* scnt  = (int*)(ws + 27513344);                     // 196 int, reserve 1024
    unsigned short* csr = (unsigned short*)(ws + 27514368); // 1.2M ushort = 2,400,000
    unsigned int* sbuf = (unsigned int*)(ws + 29914368);    // 196*SCAP*4 = 2,809,856
    float* sums = (float*)(ws + 32724224);                  // 32,768
    // total = 32,756,992 bytes

    float* dinv1 = dinv;
    float* dinv2 = dinv + NPAD;
    float* dinv3 = dinv + 2 * NPAD;

    hipMemsetAsync(scnt, 0, (size_t)NR * sizeof(int), stream);
    hipMemsetAsync(sums, 0, (size_t)GG * HH * sizeof(float), stream);

    dim3 b256(256);
    k_part<<<dim3((EE + EPB - 1) / EPB), b256, 0, stream>>>(ei, mask, scnt, sbuf);
    k_cnt<<<dim3(NR), b256, 0, stream>>>(scnt, sbuf, deg, dinv);
    k_scan1<<<dim3(NBLK3), b256, 0, stream>>>(deg, btot);
    k_scan2<<<dim3(1), dim3(1024), 0, stream>>>(btot, boff);
    k_scan3<<<dim3(NBLK3), b256, 0, stream>>>(deg, boff, rp);
    k_build<<<dim3(NR), b256, 0, stream>>>(scnt, sbuf, rp, csr);

    k_wt3<<<dim3(192), b256, 0, stream>>>(W1, W2, W3, wt1);

    dim3 ggrid((NN + 63) / 64);   // 782 blocks (gemm)
    dim3 agrid(NN / 16);          // 3125 blocks (agg)

    // layer 1: all edges (section 0)
    k_gemm_f<<<ggrid, b256, 0, stream>>>(x, wt1, h);
    k_agg<<<agrid, b256, 0, stream>>>(h, dinv1, csr, rp, b1, g, 1);
    // layer 2: mask==1 (section 1)
    k_gemm_b<<<ggrid, b256, 0, stream>>>(g, wt2, h);
    k_agg<<<agrid, b256, 0, stream>>>(h, dinv2, csr, rp + NPAD, b2, g, 1);
    // layer 3: mask==2 (section 2), no relu
    k_gemm_b<<<ggrid, b256, 0, stream>>>(g, wt3, h);
    k_agg<<<agrid, b256, 0, stream>>>(h, dinv3, csr, rp + 2 * NPAD, b3, g, 0);

    k_pool_part<<<dim3((NN + 63) / 64), dim3(128), 0, stream>>>(g, batch, sums);
    k_head<<<dim3(GG), dim3(128), 0, stream>>>(sums, batch, Wl, bl, out);
}